// Round 4
// baseline (140.666 us; speedup 1.0000x reference)
//
#include <hip/hip_runtime.h>

#define CHUNK 512
#define NBINS 32
#define NCLS  10
#define MPAD  12   // masks padded to 12 floats/voxel -> 48B stride, b128-aligned

__global__ __launch_bounds__(256, 5) void dvh_main(
    const float* __restrict__ pred, const float* __restrict__ targ,
    const float* __restrict__ mask, float* __restrict__ gD, float* __restrict__ gN,
    int chunksTotal, int chunksPerN)
{
    __shared__ float sEp[CHUNK];           // 2 KB
    __shared__ float sEt[CHUNK];           // 2 KB
    __shared__ float ml[CHUNK * MPAD];     // 24 KB  -> 28 KB total, 5 blocks/CU

    const int tid = threadIdx.x;
    const int bg  = tid & 7;               // bin-group: bins 4*bg .. 4*bg+3
    const int vg  = tid >> 3;              // voxel-group 0..31

    const float Kb = __expf(4.f * (float)bg);
    float K[4];
    K[0] = Kb;
    K[1] = Kb * 2.71828182845904523536f;
    K[2] = Kb * 7.38905609893065022723f;
    K[3] = Kb * 20.0855369231876677409f;

    const int   bgB  = (bg < 2) ? (bg + 8) : bg;   // classes 8,9 counted by bg 0,1
    const float selB = (bg < 2) ? 1.f : 0.f;

    float acc[4][NCLS];
    #pragma unroll
    for (int j = 0; j < 4; ++j)
        #pragma unroll
        for (int c = 0; c < NCLS; ++c) acc[j][c] = 0.f;
    float cnt[4] = {0.f, 0.f, 0.f, 0.f};

    // ---- T14 prefetch registers ----
    float2 rp, rt, rm[10];
    int chunk = blockIdx.x;
    if (chunk < chunksTotal) {
        const size_t vbase = (size_t)chunk * CHUNK;
        rp = ((const float2*)(pred + vbase))[tid];
        rt = ((const float2*)(targ + vbase))[tid];
        const float2* m2 = (const float2*)(mask + vbase * NCLS);
        #pragma unroll
        for (int k = 0; k < 10; ++k) rm[k] = m2[k * 256 + tid];
    }

    for (; chunk < chunksTotal; chunk += gridDim.x) {
        const float n0f = (chunk < chunksPerN) ? 1.f : 0.f;
        const float n1f = 1.f - n0f;
        const float n0s = n0f * selB, n1s = n1f * selB;

        __syncthreads();                   // previous compute done reading LDS
        // ---- stage from regs -> LDS (exp once per voxel) ----
        sEp[2*tid]   = __expf(-32.f * rp.x);
        sEp[2*tid+1] = __expf(-32.f * rp.y);
        sEt[2*tid]   = __expf(-32.f * rt.x);
        sEt[2*tid+1] = __expf(-32.f * rt.y);
        #pragma unroll
        for (int k = 0; k < 10; ++k) {
            int idx = k * 256 + tid;
            int f   = idx * 2;
            int vl  = f / 10;
            int c   = f - vl * 10;         // even: pair never splits a voxel
            *(float2*)(&ml[vl * MPAD + c]) = rm[k];
        }
        __syncthreads();

        // ---- issue next chunk's loads; they retire under the compute below ----
        int next = chunk + gridDim.x;
        if (next < chunksTotal) {
            const size_t vb2 = (size_t)next * CHUNK;
            rp = ((const float2*)(pred + vb2))[tid];
            rt = ((const float2*)(targ + vb2))[tid];
            const float2* m2 = (const float2*)(mask + vb2 * NCLS);
            #pragma unroll
            for (int k = 0; k < 10; ++k) rm[k] = m2[k * 256 + tid];
        }

        // ---- compute: thread = (voxel-group vg, bin-group bg), 16 iters ----
        #pragma unroll 2
        for (int v = vg; v < CHUNK; v += 32) {
            float ep = sEp[v], et = sEt[v];
            float de = et - ep;
            const float4* m4 = (const float4*)(ml + v * MPAD);
            float4 m0 = m4[0], m1 = m4[1], m2v = m4[2];
            float mcA = ml[v * MPAD + bg];
            float mcB = ml[v * MPAD + bgB];
            #pragma unroll
            for (int j = 0; j < 4; ++j) {
                float ap = fmaf(ep, K[j], 1.f);
                float at = fmaf(et, K[j], 1.f);
                float r  = __builtin_amdgcn_rcpf(ap * at);
                float sd = de * K[j] * r;   // sig_p - sig_t
                acc[j][0] = fmaf(sd, m0.x,  acc[j][0]);
                acc[j][1] = fmaf(sd, m0.y,  acc[j][1]);
                acc[j][2] = fmaf(sd, m0.z,  acc[j][2]);
                acc[j][3] = fmaf(sd, m0.w,  acc[j][3]);
                acc[j][4] = fmaf(sd, m1.x,  acc[j][4]);
                acc[j][5] = fmaf(sd, m1.y,  acc[j][5]);
                acc[j][6] = fmaf(sd, m1.z,  acc[j][6]);
                acc[j][7] = fmaf(sd, m1.w,  acc[j][7]);
                acc[j][8] = fmaf(sd, m2v.x, acc[j][8]);
                acc[j][9] = fmaf(sd, m2v.y, acc[j][9]);
            }
            cnt[0] = fmaf(n0f, mcA, cnt[0]);
            cnt[1] = fmaf(n1f, mcA, cnt[1]);
            cnt[2] = fmaf(n0s, mcB, cnt[2]);
            cnt[3] = fmaf(n1s, mcB, cnt[3]);
        }
    }

    // ---- reduce across the 8 voxel-groups within each wave ----
    #pragma unroll
    for (int j = 0; j < 4; ++j)
        #pragma unroll
        for (int c = 0; c < NCLS; ++c) {
            float v = acc[j][c];
            v += __shfl_xor(v, 8, 64);
            v += __shfl_xor(v, 16, 64);
            v += __shfl_xor(v, 32, 64);
            acc[j][c] = v;
        }
    #pragma unroll
    for (int s = 0; s < 4; ++s) {
        float v = cnt[s];
        v += __shfl_xor(v, 8, 64);
        v += __shfl_xor(v, 16, 64);
        v += __shfl_xor(v, 32, 64);
        cnt[s] = v;
    }
    __syncthreads();

    float* red  = ml;                      // 4 waves * 8 bg * 40 = 1280 floats
    float* redN = ml + 1280;               // 4 waves * 8 bg * 4  = 128 floats
    const int w = tid >> 6;
    if ((tid & 63) < 8) {                  // lane = bg holds vg-reduced values
        #pragma unroll
        for (int j = 0; j < 4; ++j)
            #pragma unroll
            for (int c = 0; c < NCLS; ++c)
                red[((w * 8 + bg) * 4 + j) * NCLS + c] = acc[j][c];
        #pragma unroll
        for (int s = 0; s < 4; ++s) redN[(w * 8 + bg) * 4 + s] = cnt[s];
    }
    __syncthreads();

    for (int i = tid; i < NBINS * NCLS; i += 256) {
        int b = i / NCLS, c = i - b * NCLS;
        int bgi = b >> 2, j = b & 3;
        float s = 0.f;
        #pragma unroll
        for (int ww = 0; ww < 4; ++ww)
            s += red[((ww * 8 + bgi) * 4 + j) * NCLS + c];
        atomicAdd(&gD[i], s);
    }
    if (tid < 2 * NCLS) {
        int c = tid >> 1, n = tid & 1;
        int bgi  = (c < 8) ? c : (c - 8);
        int slot = ((c < 8) ? 0 : 2) + n;
        float s = 0.f;
        #pragma unroll
        for (int ww = 0; ww < 4; ++ww)
            s += redN[(ww * 8 + bgi) * 4 + slot];
        atomicAdd(&gN[n * NCLS + c], s);
    }
}

__global__ __launch_bounds__(512) void dvh_final(
    const float* __restrict__ gD, const float* __restrict__ gN, float* __restrict__ out)
{
    __shared__ float red[512];
    int t = threadIdx.x;
    float v = 0.f;
    if (t < NBINS * NCLS) {
        int c = t % NCLS;
        float nv0 = gN[c] + 1.f;
        float nv1 = gN[NCLS + c] + 1.f;
        float w = 1.f / (nv0 * nv0) + 1.f / (nv1 * nv1);
        float d = gD[t];
        v = d * d * w;
    }
    red[t] = v;
    __syncthreads();
    for (int s = 256; s > 0; s >>= 1) {
        if (t < s) red[t] += red[t + s];
        __syncthreads();
    }
    if (t == 0) out[0] = red[0] * (1.f / 1280.f);
}

extern "C" void kernel_launch(void* const* d_in, const int* in_sizes, int n_in,
                              void* d_out, int out_size, void* d_ws, size_t ws_size,
                              hipStream_t stream) {
    const float* pred = (const float*)d_in[0];
    const float* targ = (const float*)d_in[1];
    const float* mask = (const float*)d_in[2];
    float* gD = (float*)d_ws;                       // 320 floats: Delta[bin][c]
    float* gN = (float*)((char*)d_ws + 2048);       // 20 floats: sum-mask[n][c]

    hipMemsetAsync(d_ws, 0, 4096, stream);

    int totalVox    = in_sizes[0];           // N*V = 4194304
    int chunksTotal = totalVox / CHUNK;      // 8192
    int chunksPerN  = chunksTotal / 2;       // 4096

    dvh_main<<<1280, 256, 0, stream>>>(pred, targ, mask, gD, gN, chunksTotal, chunksPerN);
    dvh_final<<<1, 512, 0, stream>>>(gD, gN, (float*)d_out);
}

// Round 5
// 82.112 us; speedup vs baseline: 1.7131x; 1.7131x over previous
//
#include <hip/hip_runtime.h>

#define CHUNK 512
#define NBINS 32
#define NCLS  10
#define MPAD  12   // masks padded to 12 floats/voxel -> 48B stride, b128-aligned

__global__ __launch_bounds__(256) void dvh_main(
    const float* __restrict__ pred, const float* __restrict__ targ,
    const float* __restrict__ mask, float* __restrict__ gD, float* __restrict__ gN,
    int chunksTotal, int chunksPerN)
{
    __shared__ float sEp[CHUNK];           // 2 KB
    __shared__ float sEt[CHUNK];           // 2 KB
    __shared__ float ml[CHUNK * MPAD];     // 24 KB  -> 28 KB total

    const int tid = threadIdx.x;
    const int bg  = tid & 7;               // bin-group: bins 4*bg .. 4*bg+3
    const int vg  = tid >> 3;              // voxel-group 0..31

    const float Kb = __expf(4.f * (float)bg);
    float K[4];
    K[0] = Kb;
    K[1] = Kb * 2.71828182845904523536f;
    K[2] = Kb * 7.38905609893065022723f;
    K[3] = Kb * 20.0855369231876677409f;

    const int   bgB  = (bg < 2) ? (bg + 8) : bg;   // classes 8,9 counted by bg 0,1
    const float selB = (bg < 2) ? 1.f : 0.f;

    float acc[4][NCLS];
    #pragma unroll
    for (int j = 0; j < 4; ++j)
        #pragma unroll
        for (int c = 0; c < NCLS; ++c) acc[j][c] = 0.f;
    float cnt[4] = {0.f, 0.f, 0.f, 0.f};

    // ---- T14 prefetch registers (24 VGPRs; plain launch_bounds so no spill) ----
    float2 rp, rt;
    float4 rm4[5];
    int chunk = blockIdx.x;
    if (chunk < chunksTotal) {
        const size_t vbase = (size_t)chunk * CHUNK;
        rp = ((const float2*)(pred + vbase))[tid];
        rt = ((const float2*)(targ + vbase))[tid];
        const float4* m4g = (const float4*)(mask + vbase * NCLS);
        #pragma unroll
        for (int k = 0; k < 5; ++k) rm4[k] = m4g[k * 256 + tid];
    }

    for (; chunk < chunksTotal; chunk += gridDim.x) {
        const float n0f = (chunk < chunksPerN) ? 1.f : 0.f;
        const float n1f = 1.f - n0f;
        const float n0s = n0f * selB, n1s = n1f * selB;

        __syncthreads();                   // previous compute done reading LDS
        // ---- stage from regs -> LDS (exp once per voxel) ----
        sEp[2*tid]   = __expf(-32.f * rp.x);
        sEp[2*tid+1] = __expf(-32.f * rp.y);
        sEt[2*tid]   = __expf(-32.f * rt.x);
        sEt[2*tid+1] = __expf(-32.f * rt.y);
        #pragma unroll
        for (int k = 0; k < 5; ++k) {
            int f   = (k * 256 + tid) * 4;     // float offset, multiple of 4
            int vl  = f / 10;
            int c   = f - vl * 10;             // even
            int f2  = f + 2;
            int vl2 = f2 / 10;
            int c2  = f2 - vl2 * 10;           // even
            *(float2*)(&ml[vl  * MPAD + c ]) = make_float2(rm4[k].x, rm4[k].y);
            *(float2*)(&ml[vl2 * MPAD + c2]) = make_float2(rm4[k].z, rm4[k].w);
        }
        __syncthreads();

        // ---- issue next chunk's loads; they retire under the compute below ----
        int next = chunk + gridDim.x;
        if (next < chunksTotal) {
            const size_t vb2 = (size_t)next * CHUNK;
            rp = ((const float2*)(pred + vb2))[tid];
            rt = ((const float2*)(targ + vb2))[tid];
            const float4* m4g = (const float4*)(mask + vb2 * NCLS);
            #pragma unroll
            for (int k = 0; k < 5; ++k) rm4[k] = m4g[k * 256 + tid];
        }

        // ---- compute: thread = (voxel-group vg, bin-group bg), 16 iters ----
        #pragma unroll 2
        for (int v = vg; v < CHUNK; v += 32) {
            float ep = sEp[v], et = sEt[v];
            float de = et - ep;
            const float4* m4 = (const float4*)(ml + v * MPAD);
            float4 m0 = m4[0], m1 = m4[1], m2v = m4[2];
            float mcA = ml[v * MPAD + bg];
            float mcB = ml[v * MPAD + bgB];
            #pragma unroll
            for (int j = 0; j < 4; ++j) {
                float ap = fmaf(ep, K[j], 1.f);
                float at = fmaf(et, K[j], 1.f);
                float r  = __builtin_amdgcn_rcpf(ap * at);
                float sd = de * K[j] * r;   // sig_p - sig_t
                acc[j][0] = fmaf(sd, m0.x,  acc[j][0]);
                acc[j][1] = fmaf(sd, m0.y,  acc[j][1]);
                acc[j][2] = fmaf(sd, m0.z,  acc[j][2]);
                acc[j][3] = fmaf(sd, m0.w,  acc[j][3]);
                acc[j][4] = fmaf(sd, m1.x,  acc[j][4]);
                acc[j][5] = fmaf(sd, m1.y,  acc[j][5]);
                acc[j][6] = fmaf(sd, m1.z,  acc[j][6]);
                acc[j][7] = fmaf(sd, m1.w,  acc[j][7]);
                acc[j][8] = fmaf(sd, m2v.x, acc[j][8]);
                acc[j][9] = fmaf(sd, m2v.y, acc[j][9]);
            }
            cnt[0] = fmaf(n0f, mcA, cnt[0]);
            cnt[1] = fmaf(n1f, mcA, cnt[1]);
            cnt[2] = fmaf(n0s, mcB, cnt[2]);
            cnt[3] = fmaf(n1s, mcB, cnt[3]);
        }
    }

    // ---- reduce across the 8 voxel-groups within each wave ----
    #pragma unroll
    for (int j = 0; j < 4; ++j)
        #pragma unroll
        for (int c = 0; c < NCLS; ++c) {
            float v = acc[j][c];
            v += __shfl_xor(v, 8, 64);
            v += __shfl_xor(v, 16, 64);
            v += __shfl_xor(v, 32, 64);
            acc[j][c] = v;
        }
    #pragma unroll
    for (int s = 0; s < 4; ++s) {
        float v = cnt[s];
        v += __shfl_xor(v, 8, 64);
        v += __shfl_xor(v, 16, 64);
        v += __shfl_xor(v, 32, 64);
        cnt[s] = v;
    }
    __syncthreads();

    float* red  = ml;                      // 4 waves * 8 bg * 40 = 1280 floats
    float* redN = ml + 1280;               // 4 waves * 8 bg * 4  = 128 floats
    const int w = tid >> 6;
    if ((tid & 63) < 8) {                  // lane = bg holds vg-reduced values
        #pragma unroll
        for (int j = 0; j < 4; ++j)
            #pragma unroll
            for (int c = 0; c < NCLS; ++c)
                red[((w * 8 + bg) * 4 + j) * NCLS + c] = acc[j][c];
        #pragma unroll
        for (int s = 0; s < 4; ++s) redN[(w * 8 + bg) * 4 + s] = cnt[s];
    }
    __syncthreads();

    for (int i = tid; i < NBINS * NCLS; i += 256) {
        int b = i / NCLS, c = i - b * NCLS;
        int bgi = b >> 2, j = b & 3;
        float s = 0.f;
        #pragma unroll
        for (int ww = 0; ww < 4; ++ww)
            s += red[((ww * 8 + bgi) * 4 + j) * NCLS + c];
        atomicAdd(&gD[i], s);
    }
    if (tid < 2 * NCLS) {
        int c = tid >> 1, n = tid & 1;
        int bgi  = (c < 8) ? c : (c - 8);
        int slot = ((c < 8) ? 0 : 2) + n;
        float s = 0.f;
        #pragma unroll
        for (int ww = 0; ww < 4; ++ww)
            s += redN[(ww * 8 + bgi) * 4 + slot];
        atomicAdd(&gN[n * NCLS + c], s);
    }
}

__global__ __launch_bounds__(512) void dvh_final(
    const float* __restrict__ gD, const float* __restrict__ gN, float* __restrict__ out)
{
    __shared__ float red[512];
    int t = threadIdx.x;
    float v = 0.f;
    if (t < NBINS * NCLS) {
        int c = t % NCLS;
        float nv0 = gN[c] + 1.f;
        float nv1 = gN[NCLS + c] + 1.f;
        float w = 1.f / (nv0 * nv0) + 1.f / (nv1 * nv1);
        float d = gD[t];
        v = d * d * w;
    }
    red[t] = v;
    __syncthreads();
    for (int s = 256; s > 0; s >>= 1) {
        if (t < s) red[t] += red[t + s];
        __syncthreads();
    }
    if (t == 0) out[0] = red[0] * (1.f / 1280.f);
}

extern "C" void kernel_launch(void* const* d_in, const int* in_sizes, int n_in,
                              void* d_out, int out_size, void* d_ws, size_t ws_size,
                              hipStream_t stream) {
    const float* pred = (const float*)d_in[0];
    const float* targ = (const float*)d_in[1];
    const float* mask = (const float*)d_in[2];
    float* gD = (float*)d_ws;                       // 320 floats: Delta[bin][c]
    float* gN = (float*)((char*)d_ws + 2048);       // 20 floats: sum-mask[n][c]

    hipMemsetAsync(d_ws, 0, 4096, stream);

    int totalVox    = in_sizes[0];           // N*V = 4194304
    int chunksTotal = totalVox / CHUNK;      // 8192
    int chunksPerN  = chunksTotal / 2;       // 4096

    dvh_main<<<1280, 256, 0, stream>>>(pred, targ, mask, gD, gN, chunksTotal, chunksPerN);
    dvh_final<<<1, 512, 0, stream>>>(gD, gN, (float*)d_out);
}